// Round 11
// baseline (955.593 us; speedup 1.0000x reference)
//
#include <hip/hip_runtime.h>
#include <hip/hip_bf16.h>

// ---------------------------------------------------------------------------
// RecurrentBattleNet: 2-layer LSTM (B=512, T=256, IN=512, H=128) + FC head.
// Round 11: fused kernel register fix. R10's 512-thr/(512,2) config capped
// the unified VGPR+AGPR file at 256/lane < the 192 weight + ~100 working
// regs needed -> per-step weight reloads from L2 on the MFMA critical path
// (VGPR=128 = exactly half the cap in arch regs; +3MB FETCH; 3x step time).
// Now: 256 thr / 4 waves / __launch_bounds__(256,1) -> 512-reg budget;
// each wave owns 32 gate-cols (2 subtiles), 384 weight regs/lane resident;
// each thread runs 2 ew units. Structure otherwise identical to R10.
// ---------------------------------------------------------------------------

#define BATCH 512
#define SEQT  256
#define INPUTD 512
#define HID   128
#define GATES 512   // 4*HID
#define RB    4     // batch rows per recurrence block

typedef __bf16 bf16_t;
typedef bf16_t bf16x4 __attribute__((ext_vector_type(4)));
typedef bf16_t bf16x8 __attribute__((ext_vector_type(8)));
typedef float  f32x4  __attribute__((ext_vector_type(4)));

__device__ __forceinline__ float sigm(float x) {
    return __builtin_amdgcn_rcpf(1.f + __expf(-x));
}
__device__ __forceinline__ float tanhfast(float x) {
    float xc = fminf(fmaxf(x, -15.f), 15.f);
    float e = __expf(2.f * xc);
    return (e - 1.f) * __builtin_amdgcn_rcpf(e + 1.f);
}

// ---------------------------------------------------------------------------
// fp32 -> bf16 conversion, vectorized (float4 in, bf16x4 out). n4 = n/4.
// ---------------------------------------------------------------------------
__global__ __launch_bounds__(256) void cvt_f32_bf16(
    const float* __restrict__ in, bf16_t* __restrict__ out, long n4)
{
    long i = (long)blockIdx.x * 256 + threadIdx.x;
    long stride = (long)gridDim.x * 256;
    for (; i < n4; i += stride) {
        float4 v = ((const float4*)in)[i];
        bf16x4 r;
        r[0] = (bf16_t)v.x; r[1] = (bf16_t)v.y;
        r[2] = (bf16_t)v.z; r[3] = (bf16_t)v.w;
        ((bf16x4*)out)[i] = r;
    }
}

// ---------------------------------------------------------------------------
// bf16 MFMA GEMM (layer-0 input projection) writing gate-major xp:
//   xp4[b>>2][t][gate][(b&3)*128 + hid]   (float)
// A-side: logical row m -> physical row (m>>tcs)*srcT + t0 + (m&tcmask).
// 128x128 tile, BK=32, 256 thr (4 waves 2x2), 16x16x32 MFMA. bn == gate.
// ---------------------------------------------------------------------------
__global__ __launch_bounds__(256) void gemm_mfma(
    const bf16_t* __restrict__ A, const bf16_t* __restrict__ W,
    const float* __restrict__ b1, const float* __restrict__ b2,
    float* __restrict__ out,
    int K, int tcs, int tcmask, int srcT, int t0)
{
    __shared__ bf16_t As[128 * 32];
    __shared__ bf16_t Bs[128 * 32];
    int tid = threadIdx.x;
    int l = tid & 63;
    int w = tid >> 6;
    int wm = w >> 1, wn = w & 1;
    int bn = blockIdx.x;
    int bm = blockIdx.y;
    int Tc = tcmask + 1;

    long aoff[2], boff[2];
    #pragma unroll
    for (int c = 0; c < 2; ++c) {
        int m = bm * 128 + (tid >> 2) + 64 * c;
        int xr = ((m >> tcs) * srcT) + t0 + (m & tcmask);
        aoff[c] = (long)xr * K + (tid & 3) * 8;
        int n = bn * 128 + (tid >> 2) + 64 * c;
        boff[c] = (long)n * K + (tid & 3) * 8;
    }

    f32x4 acc[4][4];
    #pragma unroll
    for (int i = 0; i < 4; ++i)
        #pragma unroll
        for (int j = 0; j < 4; ++j)
            acc[i][j] = (f32x4){0.f, 0.f, 0.f, 0.f};

    const int rbase = wm * 64 + (l & 15);
    const int cbase = wn * 64 + (l & 15);
    const int kfrag = (l >> 4) * 8;

    for (int kt = 0; kt < K; kt += 32) {
        __builtin_amdgcn_global_load_lds(
            (const __attribute__((address_space(1))) void*)(A + aoff[0] + kt),
            (__attribute__((address_space(3))) void*)(As + tid * 8), 16, 0, 0);
        __builtin_amdgcn_global_load_lds(
            (const __attribute__((address_space(1))) void*)(A + aoff[1] + kt),
            (__attribute__((address_space(3))) void*)(As + 2048 + tid * 8), 16, 0, 0);
        __builtin_amdgcn_global_load_lds(
            (const __attribute__((address_space(1))) void*)(W + boff[0] + kt),
            (__attribute__((address_space(3))) void*)(Bs + tid * 8), 16, 0, 0);
        __builtin_amdgcn_global_load_lds(
            (const __attribute__((address_space(1))) void*)(W + boff[1] + kt),
            (__attribute__((address_space(3))) void*)(Bs + 2048 + tid * 8), 16, 0, 0);
        __syncthreads();

        bf16x8 af[4], bfr[4];
        #pragma unroll
        for (int i = 0; i < 4; ++i)
            af[i] = *(const bf16x8*)(As + (rbase + i * 16) * 32 + kfrag);
        #pragma unroll
        for (int j = 0; j < 4; ++j)
            bfr[j] = *(const bf16x8*)(Bs + (cbase + j * 16) * 32 + kfrag);

        #pragma unroll
        for (int i = 0; i < 4; ++i)
            #pragma unroll
            for (int j = 0; j < 4; ++j)
                acc[i][j] = __builtin_amdgcn_mfma_f32_16x16x32_bf16(
                    af[i], bfr[j], acc[i][j], 0, 0, 0);
        __syncthreads();
    }

    #pragma unroll
    for (int i = 0; i < 4; ++i) {
        int m0 = bm * 128 + wm * 64 + i * 16 + (l >> 4) * 4;
        #pragma unroll
        for (int j = 0; j < 4; ++j) {
            int n = bn * 128 + wn * 64 + j * 16 + (l & 15);
            float bb = b1[n] + b2[n];
            int hid = n & 127;          // g == bn
            #pragma unroll
            for (int r = 0; r < 4; ++r) {
                int m = m0 + r;
                int b = m >> tcs;
                int t = m & tcmask;
                int br = b >> 2, brow = b & 3;
                out[(((long)br * Tc + t) * 4 + bn) * 512 + brow * 128 + hid] =
                    acc[i][j][r] + bb;
            }
        }
    }
}

// ---------------------------------------------------------------------------
// Fused two-layer LSTM recurrence, 4-wave/256-thread version.
// Wave w owns gate-cols {g*128 + w*32 .. +32} (2 subtiles c2) for both
// layers: L0 32 MFMA + L1 64 MFMA per step, 96 weight f32x4/lane resident
// under the (256,1) 512-reg budget. Thread runs 2 ew units: (tid>>7, hid)
// and (+2 rows). L1 lags one step. 2 raw barriers/step.
// ---------------------------------------------------------------------------
#define BARRIER_()                                                             \
    do {                                                                       \
        asm volatile("s_waitcnt lgkmcnt(0)" ::: "memory");                     \
        __builtin_amdgcn_s_barrier();                                          \
        __builtin_amdgcn_sched_barrier(0);                                     \
    } while (0)

#define FUSED_STEP(X0, X1, kvar)                                               \
    {                                                                          \
        bf16x8 a0[4], a1[4];                                                   \
        _Pragma("unroll")                                                      \
        for (int ks = 0; ks < 4; ++ks) {                                       \
            int ba = (col * 256 + ks * 64 + lgroup * 16) ^ ((col & 7) << 4);   \
            a0[ks] = *(const bf16x8*)((const char*)h0_lds + ba);               \
            a1[ks] = *(const bf16x8*)((const char*)h1_lds + ba);               \
        }                                                                      \
        _Pragma("unroll")                                                      \
        for (int c2 = 0; c2 < 2; ++c2) {                                       \
            f32x4 acc[4];                                                      \
            _Pragma("unroll")                                                  \
            for (int g = 0; g < 4; ++g) acc[g] = (f32x4){0.f, 0.f, 0.f, 0.f}; \
            _Pragma("unroll")                                                  \
            for (int ks = 0; ks < 4; ++ks)                                     \
                _Pragma("unroll")                                              \
                for (int g = 0; g < 4; ++g)                                    \
                    acc[g] = __builtin_amdgcn_mfma_f32_16x16x32_bf16(          \
                        a0[ks], __builtin_bit_cast(bf16x8, wreg0[c2][g][ks]),  \
                        acc[g], 0, 0, 0);                                      \
            if (lgroup == 0) {                                                 \
                _Pragma("unroll")                                              \
                for (int r = 0; r < 4; ++r) {                                  \
                    f32x4 v;                                                   \
                    v[0] = acc[0][r]; v[1] = acc[1][r];                        \
                    v[2] = acc[2][r]; v[3] = acc[3][r];                        \
                    *(f32x4*)((char*)g0_lds + r * 2048 +                       \
                              (w * 32 + c2 * 16 + col) * 16) = v;              \
                }                                                              \
            }                                                                  \
        }                                                                      \
        if (kvar > 0) {                                                        \
            _Pragma("unroll")                                                  \
            for (int c2 = 0; c2 < 2; ++c2) {                                   \
                f32x4 acc[4];                                                  \
                _Pragma("unroll")                                              \
                for (int g = 0; g < 4; ++g)                                    \
                    acc[g] = (f32x4){0.f, 0.f, 0.f, 0.f};                      \
                _Pragma("unroll")                                              \
                for (int ks = 0; ks < 4; ++ks)                                 \
                    _Pragma("unroll")                                          \
                    for (int g = 0; g < 4; ++g)                                \
                        acc[g] = __builtin_amdgcn_mfma_f32_16x16x32_bf16(      \
                            a0[ks],                                            \
                            __builtin_bit_cast(bf16x8, wregI1[c2][g][ks]),     \
                            acc[g], 0, 0, 0);                                  \
                _Pragma("unroll")                                              \
                for (int ks = 0; ks < 4; ++ks)                                 \
                    _Pragma("unroll")                                          \
                    for (int g = 0; g < 4; ++g)                                \
                        acc[g] = __builtin_amdgcn_mfma_f32_16x16x32_bf16(      \
                            a1[ks],                                            \
                            __builtin_bit_cast(bf16x8, wregH1[c2][g][ks]),     \
                            acc[g], 0, 0, 0);                                  \
                if (lgroup == 0) {                                             \
                    _Pragma("unroll")                                          \
                    for (int r = 0; r < 4; ++r) {                              \
                        f32x4 v;                                               \
                        v[0] = acc[0][r]; v[1] = acc[1][r];                    \
                        v[2] = acc[2][r]; v[3] = acc[3][r];                    \
                        *(f32x4*)((char*)g1_lds + r * 2048 +                   \
                                  (w * 32 + c2 * 16 + col) * 16) = v;          \
                    }                                                          \
                }                                                              \
            }                                                                  \
        }                                                                      \
        BARRIER_();                                                            \
        {                                                                      \
            f32x4 gva = *(const f32x4*)((const char*)g0_lds + tid * 16);       \
            f32x4 gvb = *(const f32x4*)((const char*)g0_lds + tid * 16 + 4096);\
            float zi = gva[0] + X0.x, zf = gva[1] + X0.y;                      \
            float zg = gva[2] + X0.z, zo = gva[3] + X0.w;                      \
            c0a = sigm(zf) * c0a + sigm(zi) * tanhfast(zg);                    \
            h0a = sigm(zo) * tanhfast(c0a);                                    \
            *(bf16_t*)((char*)h0_lds + hba0) = (bf16_t)h0a;                    \
            zi = gvb[0] + X1.x; zf = gvb[1] + X1.y;                            \
            zg = gvb[2] + X1.z; zo = gvb[3] + X1.w;                            \
            c0b = sigm(zf) * c0b + sigm(zi) * tanhfast(zg);                    \
            h0b = sigm(zo) * tanhfast(c0b);                                    \
            *(bf16_t*)((char*)h0_lds + hba1) = (bf16_t)h0b;                    \
        }                                                                      \
        if (kvar > 0) {                                                        \
            f32x4 gva = *(const f32x4*)((const char*)g1_lds + tid * 16);       \
            f32x4 gvb = *(const f32x4*)((const char*)g1_lds + tid * 16 + 4096);\
            float zi = gva[0] + bias1.x, zf = gva[1] + bias1.y;                \
            float zg = gva[2] + bias1.z, zo = gva[3] + bias1.w;                \
            c1a = sigm(zf) * c1a + sigm(zi) * tanhfast(zg);                    \
            h1a = sigm(zo) * tanhfast(c1a);                                    \
            *(bf16_t*)((char*)h1_lds + hba0) = (bf16_t)h1a;                    \
            zi = gvb[0] + bias1.x; zf = gvb[1] + bias1.y;                      \
            zg = gvb[2] + bias1.z; zo = gvb[3] + bias1.w;                      \
            c1b = sigm(zf) * c1b + sigm(zi) * tanhfast(zg);                    \
            h1b = sigm(zo) * tanhfast(c1b);                                    \
            *(bf16_t*)((char*)h1_lds + hba1) = (bf16_t)h1b;                    \
        }                                                                      \
        if (kvar + 2 < Tc) {                                                   \
            long o = (long)(kvar + 2) * 2048;                                  \
            X0.x = xpt[o];        X0.y = xpt[o + 512];                         \
            X0.z = xpt[o + 1024]; X0.w = xpt[o + 1536];                        \
            X1.x = xpt[o + 256];  X1.y = xpt[o + 768];                         \
            X1.z = xpt[o + 1280]; X1.w = xpt[o + 1792];                        \
        }                                                                      \
        BARRIER_();                                                            \
    }

__global__ __launch_bounds__(256, 1) void lstm_fused(
    const float* __restrict__ xp4,   // [B/4][Tc][4][512] layer-0 projection
    const bf16_t* __restrict__ Wh0,  // Whh0 bf16 [512][128]
    const bf16_t* __restrict__ Wi1,  // Wih1 bf16 [512][128]
    const bf16_t* __restrict__ Wh1,  // Whh1 bf16 [512][128]
    const float* __restrict__ bih1, const float* __restrict__ bhh1,
    float* __restrict__ h0st, float* __restrict__ c0st,
    float* __restrict__ h1st, float* __restrict__ c1st,
    int Tc, int first)
{
    __shared__ __align__(16) bf16_t h0_lds[16 * HID];     // 4 KB, swizzled
    __shared__ __align__(16) bf16_t h1_lds[16 * HID];     // 4 KB, swizzled
    __shared__ __align__(16) float  g0_lds[4 * HID * 4];  // 8 KB
    __shared__ __align__(16) float  g1_lds[4 * HID * 4];  // 8 KB
    int tid = threadIdx.x;
    int l = tid & 63;
    int w = tid >> 6;                 // wave 0..3
    int r0 = blockIdx.x * RB;

    int col = l & 15;
    int lgroup = l >> 4;              // 0..3
    int kreg = lgroup * 8;            // B fragment k offset

    // persistent weight fragments: 3 matrices x 2 subtiles x 4 gates x 4 ks
    // = 96 f32x4 = 384 regs/lane, resident under the (256,1) 512-reg budget.
    f32x4 wreg0[2][4][4], wregI1[2][4][4], wregH1[2][4][4];
    #pragma unroll
    for (int c2 = 0; c2 < 2; ++c2)
        #pragma unroll
        for (int g = 0; g < 4; ++g)
            #pragma unroll
            for (int ks = 0; ks < 4; ++ks) {
                long o = (long)(g * 128 + w * 32 + c2 * 16 + col) * HID
                         + ks * 32 + kreg;
                wreg0[c2][g][ks]  = *(const f32x4*)(Wh0 + o);
                wregI1[c2][g][ks] = *(const f32x4*)(Wi1 + o);
                wregH1[c2][g][ks] = *(const f32x4*)(Wh1 + o);
            }
    #pragma unroll
    for (int c2 = 0; c2 < 2; ++c2)
        #pragma unroll
        for (int g = 0; g < 4; ++g)
            #pragma unroll
            for (int ks = 0; ks < 4; ++ks) {
                asm volatile("" : "+v"(wreg0[c2][g][ks]));
                asm volatile("" : "+v"(wregI1[c2][g][ks]));
                asm volatile("" : "+v"(wregH1[c2][g][ks]));
            }

    // ew identity: thread runs units (erow0, ehid) and (erow0+2, ehid)
    int erow0 = tid >> 7;             // 0..1
    int erow1 = erow0 + 2;            // 2..3
    int ehid = tid & 127;
    const int hba0 = (erow0 * 256 + ehid * 2) ^ ((erow0 & 7) << 4);
    const int hba1 = (erow1 * 256 + ehid * 2) ^ ((erow1 & 7) << 4);
    float c0a = first ? 0.f : c0st[(r0 + erow0) * HID + ehid];
    float h0a = first ? 0.f : h0st[(r0 + erow0) * HID + ehid];
    float c0b = first ? 0.f : c0st[(r0 + erow1) * HID + ehid];
    float h0b = first ? 0.f : h0st[(r0 + erow1) * HID + ehid];
    float c1a = first ? 0.f : c1st[(r0 + erow0) * HID + ehid];
    float h1a = first ? 0.f : h1st[(r0 + erow0) * HID + ehid];
    float c1b = first ? 0.f : c1st[(r0 + erow1) * HID + ehid];
    float h1b = first ? 0.f : h1st[(r0 + erow1) * HID + ehid];

    // L1 biases folded in-register (same ehid for both units)
    float4 bias1;
    bias1.x = bih1[ehid]       + bhh1[ehid];
    bias1.y = bih1[128 + ehid] + bhh1[128 + ehid];
    bias1.z = bih1[256 + ehid] + bhh1[256 + ehid];
    bias1.w = bih1[384 + ehid] + bhh1[384 + ehid];

    // zero h LDS fully (256 thr x 16B = 4KB each), then stage h swizzled
    ((f32x4*)h0_lds)[tid] = (f32x4){0.f, 0.f, 0.f, 0.f};
    ((f32x4*)h1_lds)[tid] = (f32x4){0.f, 0.f, 0.f, 0.f};
    __syncthreads();
    *(bf16_t*)((char*)h0_lds + hba0) = (bf16_t)h0a;
    *(bf16_t*)((char*)h0_lds + hba1) = (bf16_t)h0b;
    *(bf16_t*)((char*)h1_lds + hba0) = (bf16_t)h1a;
    *(bf16_t*)((char*)h1_lds + hba1) = (bf16_t)h1b;
    __syncthreads();

    // per-thread xp streams (gate-major), depth-2 prefetch, named sets
    const float* xpt = xp4 + (long)blockIdx.x * Tc * 2048 + tid;
    float4 xA0, xA1, xB0, xB1;
    xA0.x = xpt[0];    xA0.y = xpt[512];
    xA0.z = xpt[1024]; xA0.w = xpt[1536];
    xA1.x = xpt[256];  xA1.y = xpt[768];
    xA1.z = xpt[1280]; xA1.w = xpt[1792];
    if (Tc > 1) {
        xB0.x = xpt[2048];        xB0.y = xpt[2048 + 512];
        xB0.z = xpt[2048 + 1024]; xB0.w = xpt[2048 + 1536];
        xB1.x = xpt[2048 + 256];  xB1.y = xpt[2048 + 768];
        xB1.z = xpt[2048 + 1280]; xB1.w = xpt[2048 + 1792];
    } else {
        xB0 = make_float4(0.f, 0.f, 0.f, 0.f);
        xB1 = xB0;
    }

    for (int tt = 0; tt < Tc; tt += 2) {
        {
            FUSED_STEP(xA0, xA1, tt)
        }
        {
            FUSED_STEP(xB0, xB1, (tt + 1))
        }
    }

    // epilogue: k = Tc, L1's final step (t1 = Tc-1) only
    {
        bf16x8 a0[4], a1[4];
        #pragma unroll
        for (int ks = 0; ks < 4; ++ks) {
            int ba = (col * 256 + ks * 64 + lgroup * 16) ^ ((col & 7) << 4);
            a0[ks] = *(const bf16x8*)((const char*)h0_lds + ba);
            a1[ks] = *(const bf16x8*)((const char*)h1_lds + ba);
        }
        #pragma unroll
        for (int c2 = 0; c2 < 2; ++c2) {
            f32x4 acc[4];
            #pragma unroll
            for (int g = 0; g < 4; ++g) acc[g] = (f32x4){0.f, 0.f, 0.f, 0.f};
            #pragma unroll
            for (int ks = 0; ks < 4; ++ks)
                #pragma unroll
                for (int g = 0; g < 4; ++g)
                    acc[g] = __builtin_amdgcn_mfma_f32_16x16x32_bf16(
                        a0[ks], __builtin_bit_cast(bf16x8, wregI1[c2][g][ks]),
                        acc[g], 0, 0, 0);
            #pragma unroll
            for (int ks = 0; ks < 4; ++ks)
                #pragma unroll
                for (int g = 0; g < 4; ++g)
                    acc[g] = __builtin_amdgcn_mfma_f32_16x16x32_bf16(
                        a1[ks], __builtin_bit_cast(bf16x8, wregH1[c2][g][ks]),
                        acc[g], 0, 0, 0);
            if (lgroup == 0) {
                #pragma unroll
                for (int r = 0; r < 4; ++r) {
                    f32x4 v;
                    v[0] = acc[0][r]; v[1] = acc[1][r];
                    v[2] = acc[2][r]; v[3] = acc[3][r];
                    *(f32x4*)((char*)g1_lds + r * 2048 +
                              (w * 32 + c2 * 16 + col) * 16) = v;
                }
            }
        }
        BARRIER_();
        f32x4 gva = *(const f32x4*)((const char*)g1_lds + tid * 16);
        f32x4 gvb = *(const f32x4*)((const char*)g1_lds + tid * 16 + 4096);
        float zi = gva[0] + bias1.x, zf = gva[1] + bias1.y;
        float zg = gva[2] + bias1.z, zo = gva[3] + bias1.w;
        c1a = sigm(zf) * c1a + sigm(zi) * tanhfast(zg);
        h1a = sigm(zo) * tanhfast(c1a);
        zi = gvb[0] + bias1.x; zf = gvb[1] + bias1.y;
        zg = gvb[2] + bias1.z; zo = gvb[3] + bias1.w;
        c1b = sigm(zf) * c1b + sigm(zi) * tanhfast(zg);
        h1b = sigm(zo) * tanhfast(c1b);
    }

    h0st[(r0 + erow0) * HID + ehid] = h0a;
    c0st[(r0 + erow0) * HID + ehid] = c0a;
    h0st[(r0 + erow1) * HID + ehid] = h0b;
    c0st[(r0 + erow1) * HID + ehid] = c0b;
    h1st[(r0 + erow0) * HID + ehid] = h1a;
    c1st[(r0 + erow0) * HID + ehid] = c1a;
    h1st[(r0 + erow1) * HID + ehid] = h1b;
    c1st[(r0 + erow1) * HID + ehid] = c1b;
}

// ---------------------------------------------------------------------------
// FC head + softmax + state copy-out. One block per batch row, 128 threads.
// out layout: probs [512*10] | h_n [2*512*128] | c_n [2*512*128]
// ---------------------------------------------------------------------------
__global__ __launch_bounds__(128) void fc_head(
    const float* __restrict__ h0st, const float* __restrict__ c0st,
    const float* __restrict__ h1st, const float* __restrict__ c1st,
    const float* __restrict__ fc1w, const float* __restrict__ fc1b,
    const float* __restrict__ fc2w, const float* __restrict__ fc2b,
    float* __restrict__ out)
{
    __shared__ float h1_s[HID];
    __shared__ float hid_s[64];
    __shared__ float log_s[10];
    int t = threadIdx.x;
    int b = blockIdx.x;

    h1_s[t] = h1st[b * HID + t];
    __syncthreads();

    if (t < 64) {
        float a = fc1b[t];
        const float* wrow = fc1w + t * HID;
        #pragma unroll 4
        for (int k = 0; k < HID; ++k) a = fmaf(wrow[k], h1_s[k], a);
        hid_s[t] = fmaxf(a, 0.f);
    }
    __syncthreads();

    if (t < 10) {
        float a = fc2b[t];
        const float* wrow = fc2w + t * 64;
        #pragma unroll 4
        for (int k = 0; k < 64; ++k) a = fmaf(wrow[k], hid_s[k], a);
        log_s[t] = a;
    }
    __syncthreads();

    if (t == 0) {
        float m = log_s[0];
        #pragma unroll
        for (int j = 1; j < 10; ++j) m = fmaxf(m, log_s[j]);
        float e[10];
        float s = 0.f;
        #pragma unroll
        for (int j = 0; j < 10; ++j) { e[j] = __expf(log_s[j] - m); s += e[j]; }
        float inv = __builtin_amdgcn_rcpf(s);
        #pragma unroll
        for (int j = 0; j < 10; ++j) out[b * 10 + j] = e[j] * inv;
    }

    float* hn = out + BATCH * 10;
    float* cn = hn + 2 * BATCH * HID;
    hn[b * HID + t] = h0st[b * HID + t];
    hn[BATCH * HID + b * HID + t] = h1_s[t];
    cn[b * HID + t] = c0st[b * HID + t];
    cn[BATCH * HID + b * HID + t] = c1st[b * HID + t];
}

// ---------------------------------------------------------------------------
extern "C" void kernel_launch(void* const* d_in, const int* in_sizes, int n_in,
                              void* d_out, int out_size, void* d_ws, size_t ws_size,
                              hipStream_t stream) {
    const float* x    = (const float*)d_in[0];
    const float* Wih0 = (const float*)d_in[1];
    const float* Whh0 = (const float*)d_in[2];
    const float* bih0 = (const float*)d_in[3];
    const float* bhh0 = (const float*)d_in[4];
    const float* Wih1 = (const float*)d_in[5];
    const float* Whh1 = (const float*)d_in[6];
    const float* bih1 = (const float*)d_in[7];
    const float* bhh1 = (const float*)d_in[8];
    const float* fc1w = (const float*)d_in[9];
    const float* fc1b = (const float*)d_in[10];
    const float* fc2w = (const float*)d_in[11];
    const float* fc2b = (const float*)d_in[12];
    float* out = (float*)d_out;

    int Tc = SEQT;
    while (Tc > 1) {
        size_t need = (size_t)BATCH * Tc * GATES * 4       // xp4
                    + (size_t)BATCH * SEQT * INPUTD * 2    // xb
                    + ((size_t)GATES * INPUTD + 3 * (size_t)GATES * HID) * 2
                    + 4 * (size_t)BATCH * HID * 4 + 256;
        if (need <= ws_size) break;
        Tc >>= 1;
    }
    int tcs = __builtin_ctz((unsigned)Tc);

    float*  xp   = (float*)d_ws;
    bf16_t* xb   = (bf16_t*)(xp + (size_t)BATCH * Tc * GATES);
    bf16_t* wb0  = xb + (size_t)BATCH * SEQT * INPUTD;
    bf16_t* wb1  = wb0 + (size_t)GATES * INPUTD;
    bf16_t* wh0b = wb1 + (size_t)GATES * HID;
    bf16_t* wh1b = wh0b + (size_t)GATES * HID;
    float*  h0st = (float*)(wh1b + (size_t)GATES * HID);
    float*  c0st = h0st + (size_t)BATCH * HID;
    float*  h1st = c0st + (size_t)BATCH * HID;
    float*  c1st = h1st + (size_t)BATCH * HID;

    cvt_f32_bf16<<<2048, 256, 0, stream>>>(x, xb, (long)BATCH * SEQT * INPUTD / 4);
    cvt_f32_bf16<<<256, 256, 0, stream>>>(Wih0, wb0, (long)GATES * INPUTD / 4);
    cvt_f32_bf16<<<64, 256, 0, stream>>>(Wih1, wb1, (long)GATES * HID / 4);
    cvt_f32_bf16<<<64, 256, 0, stream>>>(Whh0, wh0b, (long)GATES * HID / 4);
    cvt_f32_bf16<<<64, 256, 0, stream>>>(Whh1, wh1b, (long)GATES * HID / 4);

    int nchunk = SEQT / Tc;
    dim3 gemm_grid(GATES / 128, (BATCH * Tc) / 128);

    for (int ci = 0; ci < nchunk; ++ci) {
        int t0 = ci * Tc;
        gemm_mfma<<<gemm_grid, 256, 0, stream>>>(
            xb, wb0, bih0, bhh0, xp, INPUTD, tcs, Tc - 1, SEQT, t0);
        lstm_fused<<<BATCH / RB, 256, 0, stream>>>(
            xp, wh0b, wb1, wh1b, bih1, bhh1,
            h0st, c0st, h1st, c1st, Tc, ci == 0);
    }

    fc_head<<<BATCH, 128, 0, stream>>>(
        h0st, c0st, h1st, c1st, fc1w, fc1b, fc2w, fc2b, out);
}

// Round 12
// 695.899 us; speedup vs baseline: 1.3732x; 1.3732x over previous
//
#include <hip/hip_runtime.h>
#include <hip/hip_bf16.h>

// ---------------------------------------------------------------------------
// RecurrentBattleNet: 2-layer LSTM (B=512, T=256, IN=512, H=128) + FC head.
// Round 12: fused kernel, AGPR fix. R10/R11 failed because "+v" pins forced
// all 384 weight regs into the 256-entry architectural VGPR file (R11
// VGPR_Count=256 = exhausted -> spill/remat, 7040 cyc/step). gfx950 MFMA
// takes B operands from AGPR (ISA §10), so: wreg0+wregI1 (256 regs) pinned
// "+a" (AGPR), wregH1 (128) "+v". VGPR ~236 <= 256, unified 492 <= 512.
// Otherwise identical to R11 (256 thr, 4 waves, (256,1), 2 ew units/thread).
// ---------------------------------------------------------------------------

#define BATCH 512
#define SEQT  256
#define INPUTD 512
#define HID   128
#define GATES 512   // 4*HID
#define RB    4     // batch rows per recurrence block

typedef __bf16 bf16_t;
typedef bf16_t bf16x4 __attribute__((ext_vector_type(4)));
typedef bf16_t bf16x8 __attribute__((ext_vector_type(8)));
typedef float  f32x4  __attribute__((ext_vector_type(4)));

__device__ __forceinline__ float sigm(float x) {
    return __builtin_amdgcn_rcpf(1.f + __expf(-x));
}
__device__ __forceinline__ float tanhfast(float x) {
    float xc = fminf(fmaxf(x, -15.f), 15.f);
    float e = __expf(2.f * xc);
    return (e - 1.f) * __builtin_amdgcn_rcpf(e + 1.f);
}

// ---------------------------------------------------------------------------
// fp32 -> bf16 conversion, vectorized (float4 in, bf16x4 out). n4 = n/4.
// ---------------------------------------------------------------------------
__global__ __launch_bounds__(256) void cvt_f32_bf16(
    const float* __restrict__ in, bf16_t* __restrict__ out, long n4)
{
    long i = (long)blockIdx.x * 256 + threadIdx.x;
    long stride = (long)gridDim.x * 256;
    for (; i < n4; i += stride) {
        float4 v = ((const float4*)in)[i];
        bf16x4 r;
        r[0] = (bf16_t)v.x; r[1] = (bf16_t)v.y;
        r[2] = (bf16_t)v.z; r[3] = (bf16_t)v.w;
        ((bf16x4*)out)[i] = r;
    }
}

// ---------------------------------------------------------------------------
// bf16 MFMA GEMM (layer-0 input projection) writing gate-major xp:
//   xp4[b>>2][t][gate][(b&3)*128 + hid]   (float)
// A-side: logical row m -> physical row (m>>tcs)*srcT + t0 + (m&tcmask).
// 128x128 tile, BK=32, 256 thr (4 waves 2x2), 16x16x32 MFMA. bn == gate.
// ---------------------------------------------------------------------------
__global__ __launch_bounds__(256) void gemm_mfma(
    const bf16_t* __restrict__ A, const bf16_t* __restrict__ W,
    const float* __restrict__ b1, const float* __restrict__ b2,
    float* __restrict__ out,
    int K, int tcs, int tcmask, int srcT, int t0)
{
    __shared__ bf16_t As[128 * 32];
    __shared__ bf16_t Bs[128 * 32];
    int tid = threadIdx.x;
    int l = tid & 63;
    int w = tid >> 6;
    int wm = w >> 1, wn = w & 1;
    int bn = blockIdx.x;
    int bm = blockIdx.y;
    int Tc = tcmask + 1;

    long aoff[2], boff[2];
    #pragma unroll
    for (int c = 0; c < 2; ++c) {
        int m = bm * 128 + (tid >> 2) + 64 * c;
        int xr = ((m >> tcs) * srcT) + t0 + (m & tcmask);
        aoff[c] = (long)xr * K + (tid & 3) * 8;
        int n = bn * 128 + (tid >> 2) + 64 * c;
        boff[c] = (long)n * K + (tid & 3) * 8;
    }

    f32x4 acc[4][4];
    #pragma unroll
    for (int i = 0; i < 4; ++i)
        #pragma unroll
        for (int j = 0; j < 4; ++j)
            acc[i][j] = (f32x4){0.f, 0.f, 0.f, 0.f};

    const int rbase = wm * 64 + (l & 15);
    const int cbase = wn * 64 + (l & 15);
    const int kfrag = (l >> 4) * 8;

    for (int kt = 0; kt < K; kt += 32) {
        __builtin_amdgcn_global_load_lds(
            (const __attribute__((address_space(1))) void*)(A + aoff[0] + kt),
            (__attribute__((address_space(3))) void*)(As + tid * 8), 16, 0, 0);
        __builtin_amdgcn_global_load_lds(
            (const __attribute__((address_space(1))) void*)(A + aoff[1] + kt),
            (__attribute__((address_space(3))) void*)(As + 2048 + tid * 8), 16, 0, 0);
        __builtin_amdgcn_global_load_lds(
            (const __attribute__((address_space(1))) void*)(W + boff[0] + kt),
            (__attribute__((address_space(3))) void*)(Bs + tid * 8), 16, 0, 0);
        __builtin_amdgcn_global_load_lds(
            (const __attribute__((address_space(1))) void*)(W + boff[1] + kt),
            (__attribute__((address_space(3))) void*)(Bs + 2048 + tid * 8), 16, 0, 0);
        __syncthreads();

        bf16x8 af[4], bfr[4];
        #pragma unroll
        for (int i = 0; i < 4; ++i)
            af[i] = *(const bf16x8*)(As + (rbase + i * 16) * 32 + kfrag);
        #pragma unroll
        for (int j = 0; j < 4; ++j)
            bfr[j] = *(const bf16x8*)(Bs + (cbase + j * 16) * 32 + kfrag);

        #pragma unroll
        for (int i = 0; i < 4; ++i)
            #pragma unroll
            for (int j = 0; j < 4; ++j)
                acc[i][j] = __builtin_amdgcn_mfma_f32_16x16x32_bf16(
                    af[i], bfr[j], acc[i][j], 0, 0, 0);
        __syncthreads();
    }

    #pragma unroll
    for (int i = 0; i < 4; ++i) {
        int m0 = bm * 128 + wm * 64 + i * 16 + (l >> 4) * 4;
        #pragma unroll
        for (int j = 0; j < 4; ++j) {
            int n = bn * 128 + wn * 64 + j * 16 + (l & 15);
            float bb = b1[n] + b2[n];
            int hid = n & 127;          // g == bn
            #pragma unroll
            for (int r = 0; r < 4; ++r) {
                int m = m0 + r;
                int b = m >> tcs;
                int t = m & tcmask;
                int br = b >> 2, brow = b & 3;
                out[(((long)br * Tc + t) * 4 + bn) * 512 + brow * 128 + hid] =
                    acc[i][j][r] + bb;
            }
        }
    }
}

// ---------------------------------------------------------------------------
// Fused two-layer LSTM recurrence, 4-wave/256-thread, AGPR-resident weights.
// Wave w owns gate-cols {g*128 + w*32 .. +32} (2 subtiles c2) for both
// layers: L0 32 MFMA + L1 64 MFMA per step. Thread runs 2 ew units.
// L1 lags one step. 2 raw barriers/step.
// ---------------------------------------------------------------------------
#define BARRIER_()                                                             \
    do {                                                                       \
        asm volatile("s_waitcnt lgkmcnt(0)" ::: "memory");                     \
        __builtin_amdgcn_s_barrier();                                          \
        __builtin_amdgcn_sched_barrier(0);                                     \
    } while (0)

#define FUSED_STEP(X0, X1, kvar)                                               \
    {                                                                          \
        bf16x8 a0[4], a1[4];                                                   \
        _Pragma("unroll")                                                      \
        for (int ks = 0; ks < 4; ++ks) {                                       \
            int ba = (col * 256 + ks * 64 + lgroup * 16) ^ ((col & 7) << 4);   \
            a0[ks] = *(const bf16x8*)((const char*)h0_lds + ba);               \
            a1[ks] = *(const bf16x8*)((const char*)h1_lds + ba);               \
        }                                                                      \
        _Pragma("unroll")                                                      \
        for (int c2 = 0; c2 < 2; ++c2) {                                       \
            f32x4 acc[4];                                                      \
            _Pragma("unroll")                                                  \
            for (int g = 0; g < 4; ++g) acc[g] = (f32x4){0.f, 0.f, 0.f, 0.f}; \
            _Pragma("unroll")                                                  \
            for (int ks = 0; ks < 4; ++ks)                                     \
                _Pragma("unroll")                                              \
                for (int g = 0; g < 4; ++g)                                    \
                    acc[g] = __builtin_amdgcn_mfma_f32_16x16x32_bf16(          \
                        a0[ks], __builtin_bit_cast(bf16x8, wreg0[c2][g][ks]),  \
                        acc[g], 0, 0, 0);                                      \
            if (lgroup == 0) {                                                 \
                _Pragma("unroll")                                              \
                for (int r = 0; r < 4; ++r) {                                  \
                    f32x4 v;                                                   \
                    v[0] = acc[0][r]; v[1] = acc[1][r];                        \
                    v[2] = acc[2][r]; v[3] = acc[3][r];                        \
                    *(f32x4*)((char*)g0_lds + r * 2048 +                       \
                              (w * 32 + c2 * 16 + col) * 16) = v;              \
                }                                                              \
            }                                                                  \
        }                                                                      \
        if (kvar > 0) {                                                        \
            _Pragma("unroll")                                                  \
            for (int c2 = 0; c2 < 2; ++c2) {                                   \
                f32x4 acc[4];                                                  \
                _Pragma("unroll")                                              \
                for (int g = 0; g < 4; ++g)                                    \
                    acc[g] = (f32x4){0.f, 0.f, 0.f, 0.f};                      \
                _Pragma("unroll")                                              \
                for (int ks = 0; ks < 4; ++ks)                                 \
                    _Pragma("unroll")                                          \
                    for (int g = 0; g < 4; ++g)                                \
                        acc[g] = __builtin_amdgcn_mfma_f32_16x16x32_bf16(      \
                            a0[ks],                                            \
                            __builtin_bit_cast(bf16x8, wregI1[c2][g][ks]),     \
                            acc[g], 0, 0, 0);                                  \
                _Pragma("unroll")                                              \
                for (int ks = 0; ks < 4; ++ks)                                 \
                    _Pragma("unroll")                                          \
                    for (int g = 0; g < 4; ++g)                                \
                        acc[g] = __builtin_amdgcn_mfma_f32_16x16x32_bf16(      \
                            a1[ks],                                            \
                            __builtin_bit_cast(bf16x8, wregH1[c2][g][ks]),     \
                            acc[g], 0, 0, 0);                                  \
                if (lgroup == 0) {                                             \
                    _Pragma("unroll")                                          \
                    for (int r = 0; r < 4; ++r) {                              \
                        f32x4 v;                                               \
                        v[0] = acc[0][r]; v[1] = acc[1][r];                    \
                        v[2] = acc[2][r]; v[3] = acc[3][r];                    \
                        *(f32x4*)((char*)g1_lds + r * 2048 +                   \
                                  (w * 32 + c2 * 16 + col) * 16) = v;          \
                    }                                                          \
                }                                                              \
            }                                                                  \
        }                                                                      \
        BARRIER_();                                                            \
        {                                                                      \
            f32x4 gva = *(const f32x4*)((const char*)g0_lds + tid * 16);       \
            f32x4 gvb = *(const f32x4*)((const char*)g0_lds + tid * 16 + 4096);\
            float zi = gva[0] + X0.x, zf = gva[1] + X0.y;                      \
            float zg = gva[2] + X0.z, zo = gva[3] + X0.w;                      \
            c0a = sigm(zf) * c0a + sigm(zi) * tanhfast(zg);                    \
            h0a = sigm(zo) * tanhfast(c0a);                                    \
            *(bf16_t*)((char*)h0_lds + hba0) = (bf16_t)h0a;                    \
            zi = gvb[0] + X1.x; zf = gvb[1] + X1.y;                            \
            zg = gvb[2] + X1.z; zo = gvb[3] + X1.w;                            \
            c0b = sigm(zf) * c0b + sigm(zi) * tanhfast(zg);                    \
            h0b = sigm(zo) * tanhfast(c0b);                                    \
            *(bf16_t*)((char*)h0_lds + hba1) = (bf16_t)h0b;                    \
        }                                                                      \
        if (kvar > 0) {                                                        \
            f32x4 gva = *(const f32x4*)((const char*)g1_lds + tid * 16);       \
            f32x4 gvb = *(const f32x4*)((const char*)g1_lds + tid * 16 + 4096);\
            float zi = gva[0] + bias1.x, zf = gva[1] + bias1.y;                \
            float zg = gva[2] + bias1.z, zo = gva[3] + bias1.w;                \
            c1a = sigm(zf) * c1a + sigm(zi) * tanhfast(zg);                    \
            h1a = sigm(zo) * tanhfast(c1a);                                    \
            *(bf16_t*)((char*)h1_lds + hba0) = (bf16_t)h1a;                    \
            zi = gvb[0] + bias1.x; zf = gvb[1] + bias1.y;                      \
            zg = gvb[2] + bias1.z; zo = gvb[3] + bias1.w;                      \
            c1b = sigm(zf) * c1b + sigm(zi) * tanhfast(zg);                    \
            h1b = sigm(zo) * tanhfast(c1b);                                    \
            *(bf16_t*)((char*)h1_lds + hba1) = (bf16_t)h1b;                    \
        }                                                                      \
        if (kvar + 2 < Tc) {                                                   \
            long o = (long)(kvar + 2) * 2048;                                  \
            X0.x = xpt[o];        X0.y = xpt[o + 512];                         \
            X0.z = xpt[o + 1024]; X0.w = xpt[o + 1536];                        \
            X1.x = xpt[o + 256];  X1.y = xpt[o + 768];                         \
            X1.z = xpt[o + 1280]; X1.w = xpt[o + 1792];                        \
        }                                                                      \
        BARRIER_();                                                            \
    }

__global__ __launch_bounds__(256, 1) void lstm_fused(
    const float* __restrict__ xp4,   // [B/4][Tc][4][512] layer-0 projection
    const bf16_t* __restrict__ Wh0,  // Whh0 bf16 [512][128]
    const bf16_t* __restrict__ Wi1,  // Wih1 bf16 [512][128]
    const bf16_t* __restrict__ Wh1,  // Whh1 bf16 [512][128]
    const float* __restrict__ bih1, const float* __restrict__ bhh1,
    float* __restrict__ h0st, float* __restrict__ c0st,
    float* __restrict__ h1st, float* __restrict__ c1st,
    int Tc, int first)
{
    __shared__ __align__(16) bf16_t h0_lds[16 * HID];     // 4 KB, swizzled
    __shared__ __align__(16) bf16_t h1_lds[16 * HID];     // 4 KB, swizzled
    __shared__ __align__(16) float  g0_lds[4 * HID * 4];  // 8 KB
    __shared__ __align__(16) float  g1_lds[4 * HID * 4];  // 8 KB
    int tid = threadIdx.x;
    int l = tid & 63;
    int w = tid >> 6;                 // wave 0..3
    int r0 = blockIdx.x * RB;

    int col = l & 15;
    int lgroup = l >> 4;              // 0..3
    int kreg = lgroup * 8;            // B fragment k offset

    // persistent weight fragments: 3 matrices x 2 subtiles x 4 gates x 4 ks
    // = 96 f32x4 = 384 regs/lane. wreg0 + wregI1 -> AGPR (256 = exactly the
    // a-file); wregH1 -> VGPR (128 + ~110 working <= 256 v-file).
    f32x4 wreg0[2][4][4], wregI1[2][4][4], wregH1[2][4][4];
    #pragma unroll
    for (int c2 = 0; c2 < 2; ++c2)
        #pragma unroll
        for (int g = 0; g < 4; ++g)
            #pragma unroll
            for (int ks = 0; ks < 4; ++ks) {
                long o = (long)(g * 128 + w * 32 + c2 * 16 + col) * HID
                         + ks * 32 + kreg;
                wreg0[c2][g][ks]  = *(const f32x4*)(Wh0 + o);
                wregI1[c2][g][ks] = *(const f32x4*)(Wi1 + o);
                wregH1[c2][g][ks] = *(const f32x4*)(Wh1 + o);
            }
    #pragma unroll
    for (int c2 = 0; c2 < 2; ++c2)
        #pragma unroll
        for (int g = 0; g < 4; ++g)
            #pragma unroll
            for (int ks = 0; ks < 4; ++ks) {
                asm volatile("" : "+a"(wreg0[c2][g][ks]));   // AGPR-pin
                asm volatile("" : "+a"(wregI1[c2][g][ks]));  // AGPR-pin
                asm volatile("" : "+v"(wregH1[c2][g][ks]));  // VGPR-pin
            }

    // ew identity: thread runs units (erow0, ehid) and (erow0+2, ehid)
    int erow0 = tid >> 7;             // 0..1
    int erow1 = erow0 + 2;            // 2..3
    int ehid = tid & 127;
    const int hba0 = (erow0 * 256 + ehid * 2) ^ ((erow0 & 7) << 4);
    const int hba1 = (erow1 * 256 + ehid * 2) ^ ((erow1 & 7) << 4);
    float c0a = first ? 0.f : c0st[(r0 + erow0) * HID + ehid];
    float h0a = first ? 0.f : h0st[(r0 + erow0) * HID + ehid];
    float c0b = first ? 0.f : c0st[(r0 + erow1) * HID + ehid];
    float h0b = first ? 0.f : h0st[(r0 + erow1) * HID + ehid];
    float c1a = first ? 0.f : c1st[(r0 + erow0) * HID + ehid];
    float h1a = first ? 0.f : h1st[(r0 + erow0) * HID + ehid];
    float c1b = first ? 0.f : c1st[(r0 + erow1) * HID + ehid];
    float h1b = first ? 0.f : h1st[(r0 + erow1) * HID + ehid];

    // L1 biases folded in-register (same ehid for both units)
    float4 bias1;
    bias1.x = bih1[ehid]       + bhh1[ehid];
    bias1.y = bih1[128 + ehid] + bhh1[128 + ehid];
    bias1.z = bih1[256 + ehid] + bhh1[256 + ehid];
    bias1.w = bih1[384 + ehid] + bhh1[384 + ehid];

    // zero h LDS fully (256 thr x 16B = 4KB each), then stage h swizzled
    ((f32x4*)h0_lds)[tid] = (f32x4){0.f, 0.f, 0.f, 0.f};
    ((f32x4*)h1_lds)[tid] = (f32x4){0.f, 0.f, 0.f, 0.f};
    __syncthreads();
    *(bf16_t*)((char*)h0_lds + hba0) = (bf16_t)h0a;
    *(bf16_t*)((char*)h0_lds + hba1) = (bf16_t)h0b;
    *(bf16_t*)((char*)h1_lds + hba0) = (bf16_t)h1a;
    *(bf16_t*)((char*)h1_lds + hba1) = (bf16_t)h1b;
    __syncthreads();

    // per-thread xp streams (gate-major), depth-2 prefetch, named sets
    const float* xpt = xp4 + (long)blockIdx.x * Tc * 2048 + tid;
    float4 xA0, xA1, xB0, xB1;
    xA0.x = xpt[0];    xA0.y = xpt[512];
    xA0.z = xpt[1024]; xA0.w = xpt[1536];
    xA1.x = xpt[256];  xA1.y = xpt[768];
    xA1.z = xpt[1280]; xA1.w = xpt[1792];
    if (Tc > 1) {
        xB0.x = xpt[2048];        xB0.y = xpt[2048 + 512];
        xB0.z = xpt[2048 + 1024]; xB0.w = xpt[2048 + 1536];
        xB1.x = xpt[2048 + 256];  xB1.y = xpt[2048 + 768];
        xB1.z = xpt[2048 + 1280]; xB1.w = xpt[2048 + 1792];
    } else {
        xB0 = make_float4(0.f, 0.f, 0.f, 0.f);
        xB1 = xB0;
    }

    for (int tt = 0; tt < Tc; tt += 2) {
        {
            FUSED_STEP(xA0, xA1, tt)
        }
        {
            FUSED_STEP(xB0, xB1, (tt + 1))
        }
    }

    // epilogue: k = Tc, L1's final step (t1 = Tc-1) only
    {
        bf16x8 a0[4], a1[4];
        #pragma unroll
        for (int ks = 0; ks < 4; ++ks) {
            int ba = (col * 256 + ks * 64 + lgroup * 16) ^ ((col & 7) << 4);
            a0[ks] = *(const bf16x8*)((const char*)h0_lds + ba);
            a1[ks] = *(const bf16x8*)((const char*)h1_lds + ba);
        }
        #pragma unroll
        for (int c2 = 0; c2 < 2; ++c2) {
            f32x4 acc[4];
            #pragma unroll
            for (int g = 0; g < 4; ++g) acc[g] = (f32x4){0.f, 0.f, 0.f, 0.f};
            #pragma unroll
            for (int ks = 0; ks < 4; ++ks)
                #pragma unroll
                for (int g = 0; g < 4; ++g)
                    acc[g] = __builtin_amdgcn_mfma_f32_16x16x32_bf16(
                        a0[ks], __builtin_bit_cast(bf16x8, wregI1[c2][g][ks]),
                        acc[g], 0, 0, 0);
            #pragma unroll
            for (int ks = 0; ks < 4; ++ks)
                #pragma unroll
                for (int g = 0; g < 4; ++g)
                    acc[g] = __builtin_amdgcn_mfma_f32_16x16x32_bf16(
                        a1[ks], __builtin_bit_cast(bf16x8, wregH1[c2][g][ks]),
                        acc[g], 0, 0, 0);
            if (lgroup == 0) {
                #pragma unroll
                for (int r = 0; r < 4; ++r) {
                    f32x4 v;
                    v[0] = acc[0][r]; v[1] = acc[1][r];
                    v[2] = acc[2][r]; v[3] = acc[3][r];
                    *(f32x4*)((char*)g1_lds + r * 2048 +
                              (w * 32 + c2 * 16 + col) * 16) = v;
                }
            }
        }
        BARRIER_();
        f32x4 gva = *(const f32x4*)((const char*)g1_lds + tid * 16);
        f32x4 gvb = *(const f32x4*)((const char*)g1_lds + tid * 16 + 4096);
        float zi = gva[0] + bias1.x, zf = gva[1] + bias1.y;
        float zg = gva[2] + bias1.z, zo = gva[3] + bias1.w;
        c1a = sigm(zf) * c1a + sigm(zi) * tanhfast(zg);
        h1a = sigm(zo) * tanhfast(c1a);
        zi = gvb[0] + bias1.x; zf = gvb[1] + bias1.y;
        zg = gvb[2] + bias1.z; zo = gvb[3] + bias1.w;
        c1b = sigm(zf) * c1b + sigm(zi) * tanhfast(zg);
        h1b = sigm(zo) * tanhfast(c1b);
    }

    h0st[(r0 + erow0) * HID + ehid] = h0a;
    c0st[(r0 + erow0) * HID + ehid] = c0a;
    h0st[(r0 + erow1) * HID + ehid] = h0b;
    c0st[(r0 + erow1) * HID + ehid] = c0b;
    h1st[(r0 + erow0) * HID + ehid] = h1a;
    c1st[(r0 + erow0) * HID + ehid] = c1a;
    h1st[(r0 + erow1) * HID + ehid] = h1b;
    c1st[(r0 + erow1) * HID + ehid] = c1b;
}

// ---------------------------------------------------------------------------
// FC head + softmax + state copy-out. One block per batch row, 128 threads.
// out layout: probs [512*10] | h_n [2*512*128] | c_n [2*512*128]
// ---------------------------------------------------------------------------
__global__ __launch_bounds__(128) void fc_head(
    const float* __restrict__ h0st, const float* __restrict__ c0st,
    const float* __restrict__ h1st, const float* __restrict__ c1st,
    const float* __restrict__ fc1w, const float* __restrict__ fc1b,
    const float* __restrict__ fc2w, const float* __restrict__ fc2b,
    float* __restrict__ out)
{
    __shared__ float h1_s[HID];
    __shared__ float hid_s[64];
    __shared__ float log_s[10];
    int t = threadIdx.x;
    int b = blockIdx.x;

    h1_s[t] = h1st[b * HID + t];
    __syncthreads();

    if (t < 64) {
        float a = fc1b[t];
        const float* wrow = fc1w + t * HID;
        #pragma unroll 4
        for (int k = 0; k < HID; ++k) a = fmaf(wrow[k], h1_s[k], a);
        hid_s[t] = fmaxf(a, 0.f);
    }
    __syncthreads();

    if (t < 10) {
        float a = fc2b[t];
        const float* wrow = fc2w + t * 64;
        #pragma unroll 4
        for (int k = 0; k < 64; ++k) a = fmaf(wrow[k], hid_s[k], a);
        log_s[t] = a;
    }
    __syncthreads();

    if (t == 0) {
        float m = log_s[0];
        #pragma unroll
        for (int j = 1; j < 10; ++j) m = fmaxf(m, log_s[j]);
        float e[10];
        float s = 0.f;
        #pragma unroll
        for (int j = 0; j < 10; ++j) { e[j] = __expf(log_s[j] - m); s += e[j]; }
        float inv = __builtin_amdgcn_rcpf(s);
        #pragma unroll
        for (int j = 0; j < 10; ++j) out[b * 10 + j] = e[j] * inv;
    }

    float* hn = out + BATCH * 10;
    float* cn = hn + 2 * BATCH * HID;
    hn[b * HID + t] = h0st[b * HID + t];
    hn[BATCH * HID + b * HID + t] = h1_s[t];
    cn[b * HID + t] = c0st[b * HID + t];
    cn[BATCH * HID + b * HID + t] = c1st[b * HID + t];
}

// ---------------------------------------------------------------------------
extern "C" void kernel_launch(void* const* d_in, const int* in_sizes, int n_in,
                              void* d_out, int out_size, void* d_ws, size_t ws_size,
                              hipStream_t stream) {
    const float* x    = (const float*)d_in[0];
    const float* Wih0 = (const float*)d_in[1];
    const float* Whh0 = (const float*)d_in[2];
    const float* bih0 = (const float*)d_in[3];
    const float* bhh0 = (const float*)d_in[4];
    const float* Wih1 = (const float*)d_in[5];
    const float* Whh1 = (const float*)d_in[6];
    const float* bih1 = (const float*)d_in[7];
    const float* bhh1 = (const float*)d_in[8];
    const float* fc1w = (const float*)d_in[9];
    const float* fc1b = (const float*)d_in[10];
    const float* fc2w = (const float*)d_in[11];
    const float* fc2b = (const float*)d_in[12];
    float* out = (float*)d_out;

    int Tc = SEQT;
    while (Tc > 1) {
        size_t need = (size_t)BATCH * Tc * GATES * 4       // xp4
                    + (size_t)BATCH * SEQT * INPUTD * 2    // xb
                    + ((size_t)GATES * INPUTD + 3 * (size_t)GATES * HID) * 2
                    + 4 * (size_t)BATCH * HID * 4 + 256;
        if (need <= ws_size) break;
        Tc >>= 1;
    }
    int tcs = __builtin_ctz((unsigned)Tc);

    float*  xp   = (float*)d_ws;
    bf16_t* xb   = (bf16_t*)(xp + (size_t)BATCH * Tc * GATES);
    bf16_t* wb0  = xb + (size_t)BATCH * SEQT * INPUTD;
    bf16_t* wb1  = wb0 + (size_t)GATES * INPUTD;
    bf16_t* wh0b = wb1 + (size_t)GATES * HID;
    bf16_t* wh1b = wh0b + (size_t)GATES * HID;
    float*  h0st = (float*)(wh1b + (size_t)GATES * HID);
    float*  c0st = h0st + (size_t)BATCH * HID;
    float*  h1st = c0st + (size_t)BATCH * HID;
    float*  c1st = h1st + (size_t)BATCH * HID;

    cvt_f32_bf16<<<2048, 256, 0, stream>>>(x, xb, (long)BATCH * SEQT * INPUTD / 4);
    cvt_f32_bf16<<<256, 256, 0, stream>>>(Wih0, wb0, (long)GATES * INPUTD / 4);
    cvt_f32_bf16<<<64, 256, 0, stream>>>(Wih1, wb1, (long)GATES * HID / 4);
    cvt_f32_bf16<<<64, 256, 0, stream>>>(Whh0, wh0b, (long)GATES * HID / 4);
    cvt_f32_bf16<<<64, 256, 0, stream>>>(Whh1, wh1b, (long)GATES * HID / 4);

    int nchunk = SEQT / Tc;
    dim3 gemm_grid(GATES / 128, (BATCH * Tc) / 128);

    for (int ci = 0; ci < nchunk; ++ci) {
        int t0 = ci * Tc;
        gemm_mfma<<<gemm_grid, 256, 0, stream>>>(
            xb, wb0, bih0, bhh0, xp, INPUTD, tcs, Tc - 1, SEQT, t0);
        lstm_fused<<<BATCH / RB, 256, 0, stream>>>(
            xp, wh0b, wb1, wh1b, bih1, bhh1,
            h0st, c0st, h1st, c1st, Tc, ci == 0);
    }

    fc_head<<<BATCH, 128, 0, stream>>>(
        h0st, c0st, h1st, c1st, fc1w, fc1b, fc2w, fc2b, out);
}